// Round 7
// baseline (393.232 us; speedup 1.0000x reference)
//
#include <hip/hip_runtime.h>

#define HH 192
#define WW 192
#define CC 64
#define BB 8
#define SH 8
#define HWSZ (HH*WW)
#define TAU 0.1f

// ======== Kernel A: conv3x3 (64->8, SAME) + exact GELU, h interleaved [b][pix][8] ========
// 16x16 tile, 256 threads, 1 px/thread, 8-channel rounds, double-buffered LDS,
// register-prefetched staging (load r+1 issued before round r's FMA loop).
#define AT 16
#define HALO 18
#define PADX 24                       // stride%32==24 -> wave rows at banks {0,24,16,8}: 2-way = free
#define CCH 8
#define PLANE (HALO*HALO)             // 324
#define NELTS (CCH*PLANE)             // 2592
#define NSLOT 11                      // ceil(2592/256)
#define LDS_C (HALO*PADX)             // 432

__global__ __launch_bounds__(256) void conv1_gelu_kernel(
    const float* __restrict__ x, const float* __restrict__ w1, float* __restrict__ h)
{
    __shared__ float tile[2][CCH][HALO][PADX];    // 2 x 13.8 KB
    const int t  = threadIdx.x;

    // Batch-per-XCD swizzle: XCD = li&7 = batch; tiles of a batch sequential on one XCD.
    const int li  = blockIdx.x;
    const int b   = li & 7;
    const int m   = li >> 3;            // 0..143
    const int tyb = m / 12, txb = m - tyb * 12;
    const int bx  = txb * AT, by = tyb * AT;

    // Round-invariant slot precompute: idx -> (cl, iy, ix); g_off includes cl*HWSZ.
    int g_off[NSLOT], l_off[NSLOT];
    bool ok[NSLOT], inr[NSLOT];
#pragma unroll
    for (int i = 0; i < NSLOT; i++) {
        int idx = t + i * 256;
        bool v  = idx < NELTS;
        int cl  = v ? (idx / PLANE) : 0;
        int rem = idx - cl * PLANE;
        int iy  = rem / HALO;
        int ix  = rem - iy * HALO;
        int gy  = by + iy - 1;
        int gx  = bx + ix - 1;
        bool o  = v && (gy >= 0) && (gy < HH) && (gx >= 0) && (gx < WW);
        inr[i]   = v;
        ok[i]    = o;
        g_off[i] = o ? (cl * HWSZ + gy * WW + gx) : 0;   // OOB -> safe addr 0
        l_off[i] = cl * LDS_C + iy * PADX + ix;
    }

    const int tx = t & 15, ty = t >> 4;

    float acc[SH];
#pragma unroll
    for (int sh = 0; sh < SH; sh++) acc[sh] = 0.f;

    const float* xp0 = x + (size_t)b * CC * HWSZ;
    float* tbuf0 = &tile[0][0][0][0];
    float* tbuf1 = &tile[1][0][0][0];

    // prologue: load + stage round 0 into buf0
    {
        float vals[NSLOT];
#pragma unroll
        for (int i = 0; i < NSLOT; i++) vals[i] = xp0[g_off[i]];
#pragma unroll
        for (int i = 0; i < NSLOT; i++) if (!ok[i]) vals[i] = 0.f;
#pragma unroll
        for (int i = 0; i < NSLOT; i++) if (inr[i]) tbuf0[l_off[i]] = vals[i];
    }

    for (int r = 0; r < CC / CCH; r++) {
        __syncthreads();   // buf[r&1] staged; buf[(r+1)&1] free (all its readers done in r-1)
        const int cur = r & 1;
        float* tcur = cur ? tbuf1 : tbuf0;
        float* tnxt = cur ? tbuf0 : tbuf1;

        // issue next round's loads NOW; vmcnt-wait lands after the FMA loop below
        float nxt[NSLOT];
        if (r < CC / CCH - 1) {
            const float* xp = xp0 + (size_t)((r + 1) * CCH) * HWSZ;
#pragma unroll
            for (int i = 0; i < NSLOT; i++) nxt[i] = xp[g_off[i]];
        }

#pragma unroll
        for (int cl = 0; cl < CCH; cl++) {
            float win[3][3];
#pragma unroll
            for (int i = 0; i < 3; i++)
#pragma unroll
                for (int j = 0; j < 3; j++)
                    win[i][j] = tcur[cl * LDS_C + (ty + i) * PADX + (tx + j)];

            const int c = r * CCH + cl;
#pragma unroll
            for (int sh = 0; sh < SH; sh++) {
                const float* ws = w1 + ((size_t)sh * CC + c) * 9;   // uniform -> s_load
                float a = acc[sh];
                a = fmaf(win[0][0], ws[0], a);
                a = fmaf(win[0][1], ws[1], a);
                a = fmaf(win[0][2], ws[2], a);
                a = fmaf(win[1][0], ws[3], a);
                a = fmaf(win[1][1], ws[4], a);
                a = fmaf(win[1][2], ws[5], a);
                a = fmaf(win[2][0], ws[6], a);
                a = fmaf(win[2][1], ws[7], a);
                a = fmaf(win[2][2], ws[8], a);
                acc[sh] = a;
            }
        }

        // stage next round (waits vmcnt here, after compute)
        if (r < CC / CCH - 1) {
#pragma unroll
            for (int i = 0; i < NSLOT; i++) if (!ok[i]) nxt[i] = 0.f;
#pragma unroll
            for (int i = 0; i < NSLOT; i++) if (inr[i]) tnxt[l_off[i]] = nxt[i];
        }
    }

    // epilogue: exact GELU, store interleaved h[b][pix][8] as 2x float4
    const int pix = (by + ty) * WW + (bx + tx);
    float g[SH];
#pragma unroll
    for (int sh = 0; sh < SH; sh++)
        g[sh] = 0.5f * acc[sh] * (1.f + erff(acc[sh] * 0.70710678118654752f));
    float4 o0, o1;
    o0.x = g[0]; o0.y = g[1]; o0.z = g[2]; o0.w = g[3];
    o1.x = g[4]; o1.y = g[5]; o1.z = g[6]; o1.w = g[7];
    float4* hp = (float4*)&h[((size_t)b * HWSZ + pix) * SH];
    hp[0] = o0;
    hp[1] = o1;
}

// ======== Kernel B: 1x1 conv coeffs + softplus/clip + 4 bilinear samples ========
__device__ __forceinline__ float sample_x(const float* __restrict__ img,
                                          int r0, int r1, float wy, float px)
{
    px = fminf(fmaxf(px, 0.f), 191.f);
    float x0f = floorf(px);
    float wx  = px - x0f;
    int x0 = (int)x0f;
    int x1 = x0 + ((x0 < WW - 1) ? 1 : 0);
    float v00 = img[r0 + x0], v01 = img[r0 + x1];
    float v10 = img[r1 + x0], v11 = img[r1 + x1];
    float top = fmaf(wx, v01 - v00, v00);
    float bot = fmaf(wx, v11 - v10, v10);
    return fmaf(wy, bot - top, top);
}

__device__ __forceinline__ float sample_y(const float* __restrict__ img,
                                          int x0, int x1, float wx, float py)
{
    py = fminf(fmaxf(py, 0.f), 191.f);
    float y0f = floorf(py);
    float wy  = py - y0f;
    int y0 = (int)y0f;
    int r0 = y0 * WW;
    int r1 = r0 + ((y0 < HH - 1) ? WW : 0);
    float v00 = img[r0 + x0], v01 = img[r0 + x1];
    float v10 = img[r1 + x0], v11 = img[r1 + x1];
    float top = fmaf(wx, v01 - v00, v00);
    float bot = fmaf(wx, v11 - v10, v10);
    return fmaf(wy, bot - top, top);
}

#define TILES_PER_PLANE 144   // 12x12 tiles of 16x16
#define NPLANES (BB*CC)       // 512

__global__ __launch_bounds__(256) void coeff_sample_kernel(
    const float* __restrict__ x, const float* __restrict__ hbuf,
    const float* __restrict__ w2, const float* __restrict__ b2,
    const float* __restrict__ log_scale, float* __restrict__ out)
{
    // XCD-aware swizzle: all 144 tiles of one (b,c) plane land on one XCD.
    const int li = blockIdx.x;
    const int rr = li & 7;
    const int m  = li >> 3;
    const int q  = m / TILES_PER_PLANE;
    const int tt = m - q * TILES_PER_PLANE;
    const int bc = (q << 3) | rr;          // plane id: b*64 + c
    const int tyb = tt / 12, txb = tt - tyb * 12;

    const int t  = threadIdx.x;
    const int tx = t & 15;
    const int ty = t >> 4;
    const int xo = txb * 16 + tx;
    const int y  = tyb * 16 + ty;
    const int c  = bc & 63;
    const int pix = y * WW + xo;

    // h interleaved [b][pix][8]: two float4 loads
    const float4* hp4 = (const float4*)&hbuf[((size_t)(bc >> 6) * HWSZ + pix) * SH];
    float4 h0 = hp4[0], h1 = hp4[1];
    float hk[SH] = {h0.x, h0.y, h0.z, h0.w, h1.x, h1.y, h1.z, h1.w};

    const int c4 = c * 4;
    float coeff[4];
#pragma unroll
    for (int j = 0; j < 4; j++) {
        const float* wr = w2 + (size_t)(c4 + j) * SH;  // uniform per block
        float s = b2[c4 + j];
#pragma unroll
        for (int k = 0; k < SH; k++) s = fmaf(hk[k], wr[k], s);
        coeff[j] = s;
    }

    // softplus (stable): max(z,0) + log(1+exp(-|z|))
    float z  = coeff[0];
    float a  = fmaxf(z, 0.f) + __logf(1.f + __expf(-fabsf(z)));
    float s  = __builtin_amdgcn_sqrtf(fmaf(a, TAU, 1e-8f));
    float dx = coeff[1] * TAU;
    float dy = coeff[2] * TAU;
    float cc = fminf(fmaxf(coeff[3], -5.f), 5.f);

    const float* img = x + (size_t)bc * HWSZ;
    const float px0 = (float)xo + dx * 95.5f;   // (W-1)/2 = 95.5
    const float py0 = (float)y  + dy * 95.5f;
    const float sp  = s * 95.5f;

    float u;
    {   // u_px + u_nx share the y interpolation state
        float py  = fminf(fmaxf(py0, 0.f), 191.f);
        float y0f = floorf(py);
        float wy  = py - y0f;
        int y0 = (int)y0f;
        int r0 = y0 * WW;
        int r1 = r0 + ((y0 < HH - 1) ? WW : 0);
        u = sample_x(img, r0, r1, wy, px0 + sp)
          + sample_x(img, r0, r1, wy, px0 - sp);
    }
    {   // u_py + u_ny share the x interpolation state
        float px  = fminf(fmaxf(px0, 0.f), 191.f);
        float x0f = floorf(px);
        float wx  = px - x0f;
        int x0 = (int)x0f;
        int x1 = x0 + ((x0 < WW - 1) ? 1 : 0);
        u += sample_y(img, x0, x1, wx, py0 + sp)
           + sample_y(img, x0, x1, wx, py0 - sp);
    }

    float xv    = img[pix];
    float scale = __expf(log_scale[0]);
    out[(size_t)bc * HWSZ + pix] = scale * fmaf(0.25f, u, TAU * cc * xv);
}

extern "C" void kernel_launch(void* const* d_in, const int* in_sizes, int n_in,
                              void* d_out, int out_size, void* d_ws, size_t ws_size,
                              hipStream_t stream)
{
    const float* x   = (const float*)d_in[0];
    const float* w1  = (const float*)d_in[1];
    const float* w2  = (const float*)d_in[2];
    const float* b2  = (const float*)d_in[3];
    const float* ls  = (const float*)d_in[4];
    float* out = (float*)d_out;
    float* h   = (float*)d_ws;        // B*HW*8 floats = 9.4 MB, interleaved [b][pix][8]

    dim3 blk(256);
    conv1_gelu_kernel<<<dim3(12 * 12 * BB), blk, 0, stream>>>(x, w1, h);

    coeff_sample_kernel<<<dim3(NPLANES * TILES_PER_PLANE), blk, 0, stream>>>(
        x, h, w2, b2, ls, out);
}

// Round 8
// 289.254 us; speedup vs baseline: 1.3595x; 1.3595x over previous
//
#include <hip/hip_runtime.h>

#define HH 192
#define WW 192
#define CC 64
#define BB 8
#define SH 8
#define HWSZ (HH*WW)
#define TAU 0.1f

// ======== Kernel A: direct conv3x3 (64->8, SAME) + exact GELU ========
// No LDS, no barriers: per thread 1 px, 9 imm-offset loads + 72 FMA per channel.
// L1 serves window overlap; occupancy is VGPR-limited; compiler pipelines loads.
__global__ __launch_bounds__(256) void conv1_gelu_kernel(
    const float* __restrict__ x, const float* __restrict__ w1, float* __restrict__ h)
{
    // Batch-per-XCD swizzle: XCD = li&7 = batch; tiles of a batch raster-ordered on one XCD.
    const int li  = blockIdx.x;
    const int b   = li & 7;
    const int m   = li >> 3;             // 0..143
    const int tyb = m / 12, txb = m - tyb * 12;

    const int t  = threadIdx.x;
    const int tx = t & 15, ty = t >> 4;
    const int xo = txb * 16 + tx;
    const int yo = tyb * 16 + ty;
    const int pix = yo * WW + xo;

    const float* xb = x + (size_t)b * CC * HWSZ;

    float acc[SH];
#pragma unroll
    for (int sh = 0; sh < SH; sh++) acc[sh] = 0.f;

    const bool border = (txb == 0) | (txb == 11) | (tyb == 0) | (tyb == 11);

    if (!border) {
        // interior: 9 loads at fixed immediate offsets from a per-channel base
        const float* p = xb + pix;
#pragma unroll 2
        for (int c = 0; c < CC; c++) {
            const float* pc = p + (size_t)c * HWSZ;
            float v[9];
            v[0] = pc[-WW - 1]; v[1] = pc[-WW]; v[2] = pc[-WW + 1];
            v[3] = pc[-1];      v[4] = pc[0];   v[5] = pc[1];
            v[6] = pc[WW - 1];  v[7] = pc[WW];  v[8] = pc[WW + 1];
            const float* wc = w1 + c * 9;
#pragma unroll
            for (int sh = 0; sh < SH; sh++) {
                const float* ws = wc + (size_t)sh * CC * 9;   // uniform -> s_load
                float a = acc[sh];
#pragma unroll
                for (int k = 0; k < 9; k++) a = fmaf(v[k], ws[k], a);
                acc[sh] = a;
            }
        }
    } else {
        // border ring: clamped addresses + zero masks (round-invariant)
        const int ym1 = max(yo - 1, 0), yp1 = min(yo + 1, HH - 1);
        const int xm1 = max(xo - 1, 0), xp1 = min(xo + 1, WW - 1);
        const int r0 = ym1 * WW, r1 = yo * WW, r2 = yp1 * WW;
        const bool vy0 = yo > 0, vy2 = yo < HH - 1, vx0 = xo > 0, vx2 = xo < WW - 1;
        int  o[9]  = {r0 + xm1, r0 + xo, r0 + xp1,
                      r1 + xm1, r1 + xo, r1 + xp1,
                      r2 + xm1, r2 + xo, r2 + xp1};
        bool mk[9] = {vy0 && vx0, vy0, vy0 && vx2,
                      vx0,        true, vx2,
                      vy2 && vx0, vy2, vy2 && vx2};
#pragma unroll 2
        for (int c = 0; c < CC; c++) {
            const float* pc = xb + (size_t)c * HWSZ;
            float v[9];
#pragma unroll
            for (int k = 0; k < 9; k++) v[k] = pc[o[k]];
#pragma unroll
            for (int k = 0; k < 9; k++) if (!mk[k]) v[k] = 0.f;
            const float* wc = w1 + c * 9;
#pragma unroll
            for (int sh = 0; sh < SH; sh++) {
                const float* ws = wc + (size_t)sh * CC * 9;
                float a = acc[sh];
#pragma unroll
                for (int k = 0; k < 9; k++) a = fmaf(v[k], ws[k], a);
                acc[sh] = a;
            }
        }
    }

    // epilogue: exact GELU, store interleaved h[b][pix][8] as 2x float4
    float g[SH];
#pragma unroll
    for (int sh = 0; sh < SH; sh++)
        g[sh] = 0.5f * acc[sh] * (1.f + erff(acc[sh] * 0.70710678118654752f));
    float4 o0, o1;
    o0.x = g[0]; o0.y = g[1]; o0.z = g[2]; o0.w = g[3];
    o1.x = g[4]; o1.y = g[5]; o1.z = g[6]; o1.w = g[7];
    float4* hp = (float4*)&h[((size_t)b * HWSZ + pix) * SH];
    hp[0] = o0;
    hp[1] = o1;
}

// ======== Kernel B: 1x1 conv coeffs + softplus/clip + 4 bilinear samples ========
__device__ __forceinline__ float sample_x(const float* __restrict__ img,
                                          int r0, int r1, float wy, float px)
{
    px = fminf(fmaxf(px, 0.f), 191.f);
    float x0f = floorf(px);
    float wx  = px - x0f;
    int x0 = (int)x0f;
    int x1 = x0 + ((x0 < WW - 1) ? 1 : 0);
    float v00 = img[r0 + x0], v01 = img[r0 + x1];
    float v10 = img[r1 + x0], v11 = img[r1 + x1];
    float top = fmaf(wx, v01 - v00, v00);
    float bot = fmaf(wx, v11 - v10, v10);
    return fmaf(wy, bot - top, top);
}

__device__ __forceinline__ float sample_y(const float* __restrict__ img,
                                          int x0, int x1, float wx, float py)
{
    py = fminf(fmaxf(py, 0.f), 191.f);
    float y0f = floorf(py);
    float wy  = py - y0f;
    int y0 = (int)y0f;
    int r0 = y0 * WW;
    int r1 = r0 + ((y0 < HH - 1) ? WW : 0);
    float v00 = img[r0 + x0], v01 = img[r0 + x1];
    float v10 = img[r1 + x0], v11 = img[r1 + x1];
    float top = fmaf(wx, v01 - v00, v00);
    float bot = fmaf(wx, v11 - v10, v10);
    return fmaf(wy, bot - top, top);
}

#define TILES_PER_PLANE 144   // 12x12 tiles of 16x16
#define NPLANES (BB*CC)       // 512

__global__ __launch_bounds__(256) void coeff_sample_kernel(
    const float* __restrict__ x, const float* __restrict__ hbuf,
    const float* __restrict__ w2, const float* __restrict__ b2,
    const float* __restrict__ log_scale, float* __restrict__ out)
{
    // XCD-aware swizzle: all 144 tiles of one (b,c) plane land on one XCD.
    const int li = blockIdx.x;
    const int rr = li & 7;
    const int m  = li >> 3;
    const int q  = m / TILES_PER_PLANE;
    const int tt = m - q * TILES_PER_PLANE;
    const int bc = (q << 3) | rr;          // plane id: b*64 + c
    const int tyb = tt / 12, txb = tt - tyb * 12;

    const int t  = threadIdx.x;
    const int tx = t & 15;
    const int ty = t >> 4;
    const int xo = txb * 16 + tx;
    const int y  = tyb * 16 + ty;
    const int c  = bc & 63;
    const int pix = y * WW + xo;

    // h interleaved [b][pix][8]: two float4 loads
    const float4* hp4 = (const float4*)&hbuf[((size_t)(bc >> 6) * HWSZ + pix) * SH];
    float4 h0 = hp4[0], h1 = hp4[1];
    float hk[SH] = {h0.x, h0.y, h0.z, h0.w, h1.x, h1.y, h1.z, h1.w};

    const int c4 = c * 4;
    float coeff[4];
#pragma unroll
    for (int j = 0; j < 4; j++) {
        const float* wr = w2 + (size_t)(c4 + j) * SH;  // uniform per block
        float s = b2[c4 + j];
#pragma unroll
        for (int k = 0; k < SH; k++) s = fmaf(hk[k], wr[k], s);
        coeff[j] = s;
    }

    // softplus (stable): max(z,0) + log(1+exp(-|z|))
    float z  = coeff[0];
    float a  = fmaxf(z, 0.f) + __logf(1.f + __expf(-fabsf(z)));
    float s  = __builtin_amdgcn_sqrtf(fmaf(a, TAU, 1e-8f));
    float dx = coeff[1] * TAU;
    float dy = coeff[2] * TAU;
    float cc = fminf(fmaxf(coeff[3], -5.f), 5.f);

    const float* img = x + (size_t)bc * HWSZ;
    const float px0 = (float)xo + dx * 95.5f;   // (W-1)/2 = 95.5
    const float py0 = (float)y  + dy * 95.5f;
    const float sp  = s * 95.5f;

    float u;
    {   // u_px + u_nx share the y interpolation state
        float py  = fminf(fmaxf(py0, 0.f), 191.f);
        float y0f = floorf(py);
        float wy  = py - y0f;
        int y0 = (int)y0f;
        int r0 = y0 * WW;
        int r1 = r0 + ((y0 < HH - 1) ? WW : 0);
        u = sample_x(img, r0, r1, wy, px0 + sp)
          + sample_x(img, r0, r1, wy, px0 - sp);
    }
    {   // u_py + u_ny share the x interpolation state
        float px  = fminf(fmaxf(px0, 0.f), 191.f);
        float x0f = floorf(px);
        float wx  = px - x0f;
        int x0 = (int)x0f;
        int x1 = x0 + ((x0 < WW - 1) ? 1 : 0);
        u += sample_y(img, x0, x1, wx, py0 + sp)
           + sample_y(img, x0, x1, wx, py0 - sp);
    }

    float xv    = img[pix];
    float scale = __expf(log_scale[0]);
    out[(size_t)bc * HWSZ + pix] = scale * fmaf(0.25f, u, TAU * cc * xv);
}

extern "C" void kernel_launch(void* const* d_in, const int* in_sizes, int n_in,
                              void* d_out, int out_size, void* d_ws, size_t ws_size,
                              hipStream_t stream)
{
    const float* x   = (const float*)d_in[0];
    const float* w1  = (const float*)d_in[1];
    const float* w2  = (const float*)d_in[2];
    const float* b2  = (const float*)d_in[3];
    const float* ls  = (const float*)d_in[4];
    float* out = (float*)d_out;
    float* h   = (float*)d_ws;        // B*HW*8 floats = 9.4 MB, interleaved [b][pix][8]

    dim3 blk(256);
    conv1_gelu_kernel<<<dim3(12 * 12 * BB), blk, 0, stream>>>(x, w1, h);

    coeff_sample_kernel<<<dim3(NPLANES * TILES_PER_PLANE), blk, 0, stream>>>(
        x, h, w2, b2, ls, out);
}

// Round 9
// 280.400 us; speedup vs baseline: 1.4024x; 1.0316x over previous
//
#include <hip/hip_runtime.h>

#define HH 192
#define WW 192
#define CC 64
#define BB 8
#define SH 8
#define HWSZ (HH*WW)
#define TAU 0.1f

// ======== Kernel A0: transpose w1 [sh][c][9] -> wt [c][sh][9] (contiguous per channel) ========
__global__ __launch_bounds__(256) void transpose_w1_kernel(
    const float* __restrict__ w1, float* __restrict__ wt)
{
    int i = blockIdx.x * 256 + threadIdx.x;          // 0..4607
    if (i < CC * SH * 9) {
        int c  = i / (SH * 9);
        int r  = i - c * (SH * 9);
        int sh = r / 9;
        int k  = r - sh * 9;
        wt[i] = w1[((size_t)sh * CC + c) * 9 + k];
    }
}

// ======== Kernel A: direct conv3x3 (64->8, SAME) + exact GELU ========
// No LDS/barriers. Per thread 1 px: per channel 9 imm-offset loads + 72 FMA,
// weights from wt[c][8][9] (contiguous 288B/channel -> few s_load_dwordx16).
__global__ __launch_bounds__(256) void conv1_gelu_kernel(
    const float* __restrict__ x, const float* __restrict__ wt, float* __restrict__ h)
{
    // Batch-per-XCD swizzle: XCD = li&7 = batch.
    const int li  = blockIdx.x;
    const int b   = li & 7;
    const int m   = li >> 3;             // 0..143
    const int tyb = m / 12, txb = m - tyb * 12;

    const int t  = threadIdx.x;
    const int tx = t & 15, ty = t >> 4;
    const int xo = txb * 16 + tx;
    const int yo = tyb * 16 + ty;
    const int pix = yo * WW + xo;

    const float* xb = x + (size_t)b * CC * HWSZ;

    float acc[SH];
#pragma unroll
    for (int sh = 0; sh < SH; sh++) acc[sh] = 0.f;

    const bool border = (txb == 0) | (txb == 11) | (tyb == 0) | (tyb == 11);

    if (!border) {
        const float* p = xb + pix;
        for (int c = 0; c < CC; c++) {
            const float* pc = p + (size_t)c * HWSZ;
            float v[9];
            v[0] = pc[-WW - 1]; v[1] = pc[-WW]; v[2] = pc[-WW + 1];
            v[3] = pc[-1];      v[4] = pc[0];   v[5] = pc[1];
            v[6] = pc[WW - 1];  v[7] = pc[WW];  v[8] = pc[WW + 1];
            const float* ws = wt + c * (SH * 9);    // uniform, contiguous 288B
#pragma unroll
            for (int sh = 0; sh < SH; sh++) {
                float a = acc[sh];
#pragma unroll
                for (int k = 0; k < 9; k++) a = fmaf(v[k], ws[sh * 9 + k], a);
                acc[sh] = a;
            }
        }
    } else {
        const int ym1 = max(yo - 1, 0), yp1 = min(yo + 1, HH - 1);
        const int xm1 = max(xo - 1, 0), xp1 = min(xo + 1, WW - 1);
        const int r0 = ym1 * WW, r1 = yo * WW, r2 = yp1 * WW;
        const bool vy0 = yo > 0, vy2 = yo < HH - 1, vx0 = xo > 0, vx2 = xo < WW - 1;
        int  o[9]  = {r0 + xm1, r0 + xo, r0 + xp1,
                      r1 + xm1, r1 + xo, r1 + xp1,
                      r2 + xm1, r2 + xo, r2 + xp1};
        bool mk[9] = {vy0 && vx0, vy0, vy0 && vx2,
                      vx0,        true, vx2,
                      vy2 && vx0, vy2, vy2 && vx2};
        for (int c = 0; c < CC; c++) {
            const float* pc = xb + (size_t)c * HWSZ;
            float v[9];
#pragma unroll
            for (int k = 0; k < 9; k++) v[k] = pc[o[k]];
#pragma unroll
            for (int k = 0; k < 9; k++) if (!mk[k]) v[k] = 0.f;
            const float* ws = wt + c * (SH * 9);
#pragma unroll
            for (int sh = 0; sh < SH; sh++) {
                float a = acc[sh];
#pragma unroll
                for (int k = 0; k < 9; k++) a = fmaf(v[k], ws[sh * 9 + k], a);
                acc[sh] = a;
            }
        }
    }

    // epilogue: exact GELU, store interleaved h[b][pix][8] as 2x float4
    float g[SH];
#pragma unroll
    for (int sh = 0; sh < SH; sh++)
        g[sh] = 0.5f * acc[sh] * (1.f + erff(acc[sh] * 0.70710678118654752f));
    float4 o0, o1;
    o0.x = g[0]; o0.y = g[1]; o0.z = g[2]; o0.w = g[3];
    o1.x = g[4]; o1.y = g[5]; o1.z = g[6]; o1.w = g[7];
    float4* hp = (float4*)&h[((size_t)b * HWSZ + pix) * SH];
    hp[0] = o0;
    hp[1] = o1;
}

// ======== Kernel B: 1x1 conv coeffs + softplus/clip + 4 bilinear samples ========
// Pair-load trick: v00/v01 adjacent except at x=191 clamp -> one float2 load at
// min(x0,190) + cndmask. 8 dwordx2 gathers instead of 16 dword. 32-bit offsets.
#define TILES_PER_PLANE 144   // 12x12 tiles of 16x16
#define NPLANES (BB*CC)       // 512

__global__ __launch_bounds__(256) void coeff_sample_kernel(
    const float* __restrict__ x, const float* __restrict__ hbuf,
    const float* __restrict__ w2, const float* __restrict__ b2,
    const float* __restrict__ log_scale, float* __restrict__ out)
{
    // XCD-aware swizzle: all 144 tiles of one (b,c) plane land on one XCD.
    const int li = blockIdx.x;
    const int rr = li & 7;
    const int m  = li >> 3;
    const int q  = m / TILES_PER_PLANE;
    const int tt = m - q * TILES_PER_PLANE;
    const int bc = (q << 3) | rr;          // plane id: b*64 + c
    const int tyb = tt / 12, txb = tt - tyb * 12;

    const int t  = threadIdx.x;
    const int tx = t & 15;
    const int ty = t >> 4;
    const int xo = txb * 16 + tx;
    const int y  = tyb * 16 + ty;
    const int c  = bc & 63;
    const int pix = y * WW + xo;

    // h interleaved [b][pix][8]: two float4 loads
    const float4* hp4 = (const float4*)&hbuf[((size_t)(bc >> 6) * HWSZ + pix) * SH];
    float4 h0 = hp4[0], h1 = hp4[1];
    float hk[SH] = {h0.x, h0.y, h0.z, h0.w, h1.x, h1.y, h1.z, h1.w};

    const int c4 = c * 4;
    float coeff[4];
#pragma unroll
    for (int j = 0; j < 4; j++) {
        const float* wr = w2 + (size_t)(c4 + j) * SH;  // uniform per block
        float s = b2[c4 + j];
#pragma unroll
        for (int k = 0; k < SH; k++) s = fmaf(hk[k], wr[k], s);
        coeff[j] = s;
    }

    // softplus (stable): max(z,0) + log(1+exp(-|z|))
    float z  = coeff[0];
    float a  = fmaxf(z, 0.f) + __logf(1.f + __expf(-fabsf(z)));
    float s  = __builtin_amdgcn_sqrtf(fmaf(a, TAU, 1e-8f));
    float dx = coeff[1] * TAU;
    float dy = coeff[2] * TAU;
    float cc = __builtin_amdgcn_fmed3f(coeff[3], -5.f, 5.f);

    const float* img = x + (size_t)bc * HWSZ;
    const float px0 = (float)xo + dx * 95.5f;   // (W-1)/2 = 95.5
    const float py0 = (float)y  + dy * 95.5f;
    const float sp  = s * 95.5f;

    float u;
    {   // u_px + u_nx: shared y state, pair-loaded rows
        float pyc = __builtin_amdgcn_fmed3f(py0, 0.f, 191.f);
        float y0f = floorf(pyc);
        float wy  = pyc - y0f;
        int y0 = (int)y0f;
        unsigned r0 = (unsigned)(y0 * WW);
        unsigned r1 = r0 + ((y0 < HH - 1) ? WW : 0);
        u = 0.f;
#pragma unroll
        for (int sgn = 0; sgn < 2; sgn++) {
            float px  = sgn ? (px0 - sp) : (px0 + sp);
            float pxc = __builtin_amdgcn_fmed3f(px, 0.f, 191.f);
            float x0f = floorf(pxc);
            float wx  = pxc - x0f;
            int  x0 = (int)x0f;
            bool hi = x0 > WW - 2;                     // x0 == 191
            unsigned xc = (unsigned)min(x0, WW - 2);
            float2 t0 = *(const float2*)(img + (r0 + xc));
            float2 t1 = *(const float2*)(img + (r1 + xc));
            float v00 = hi ? t0.y : t0.x;
            float v10 = hi ? t1.y : t1.x;
            float top = fmaf(wx, t0.y - v00, v00);
            float bot = fmaf(wx, t1.y - v10, v10);
            u += fmaf(wy, bot - top, top);
        }
    }
    {   // u_py + u_ny: shared x state (pair columns), per-sample y state
        float pxc = __builtin_amdgcn_fmed3f(px0, 0.f, 191.f);
        float x0f = floorf(pxc);
        float wx  = pxc - x0f;
        int  x0 = (int)x0f;
        bool hi = x0 > WW - 2;
        unsigned xc = (unsigned)min(x0, WW - 2);
#pragma unroll
        for (int sgn = 0; sgn < 2; sgn++) {
            float py  = sgn ? (py0 - sp) : (py0 + sp);
            float pyc = __builtin_amdgcn_fmed3f(py, 0.f, 191.f);
            float y0f = floorf(pyc);
            float wy  = pyc - y0f;
            int y0 = (int)y0f;
            unsigned r0 = (unsigned)(y0 * WW);
            unsigned r1 = r0 + ((y0 < HH - 1) ? WW : 0);
            float2 t0 = *(const float2*)(img + (r0 + xc));
            float2 t1 = *(const float2*)(img + (r1 + xc));
            float v00 = hi ? t0.y : t0.x;
            float v10 = hi ? t1.y : t1.x;
            float top = fmaf(wx, t0.y - v00, v00);
            float bot = fmaf(wx, t1.y - v10, v10);
            u += fmaf(wy, bot - top, top);
        }
    }

    float xv    = img[(unsigned)pix];
    float scale = __expf(log_scale[0]);
    out[(size_t)bc * HWSZ + pix] = scale * fmaf(0.25f, u, TAU * cc * xv);
}

extern "C" void kernel_launch(void* const* d_in, const int* in_sizes, int n_in,
                              void* d_out, int out_size, void* d_ws, size_t ws_size,
                              hipStream_t stream)
{
    const float* x   = (const float*)d_in[0];
    const float* w1  = (const float*)d_in[1];
    const float* w2  = (const float*)d_in[2];
    const float* b2  = (const float*)d_in[3];
    const float* ls  = (const float*)d_in[4];
    float* out = (float*)d_out;
    float* h   = (float*)d_ws;        // B*HW*8 floats = 9.4 MB, interleaved [b][pix][8]

    // wt lives in the tail of d_out: read by conv, overwritten later by coeff_sample
    float* wt = out + (size_t)out_size - CC * SH * 9;

    dim3 blk(256);
    transpose_w1_kernel<<<dim3((CC * SH * 9 + 255) / 256), blk, 0, stream>>>(w1, wt);

    conv1_gelu_kernel<<<dim3(12 * 12 * BB), blk, 0, stream>>>(x, wt, h);

    coeff_sample_kernel<<<dim3(NPLANES * TILES_PER_PLANE), blk, 0, stream>>>(
        x, h, w2, b2, ls, out);
}